// Round 1
// baseline (384.872 us; speedup 1.0000x reference)
//
#include <hip/hip_runtime.h>
#include <stdint.h>

// CostVolume: out[b, d=(dy+4)*9+(dx+4), h, w] =
//   leaky_relu( mean_c( x1[b,c,h,w] * x2[b,c,h+dy,w+dx] ), 0.1 ), zero-padded x2.
//
// bf16 MFMA 16x16x32 along w: M = x1 w-positions (16), N = staged x2 columns,
// K = channels. Each wave owns one (h-row, M-tile); 9 dy x 2 N-tiles = 18 MFMA
// per k-chunk; 9 dx diagonals extracted in the epilogue via LDS transpose.
//
// This version software-pipelines the k-loop:
//   - chunk k+1's 40 global loads (32 x2 + 8 x1) are issued BEFORE chunk k's
//     MFMA phase and consumed (cvt+ds_write) after it -> load latency hides
//     under the barrier wait + MFMA of the current chunk.
//   - LDS x2 tile is double-buffered -> ONE barrier per chunk (was two).
//   - the barrier is a raw lgkmcnt(0)+s_barrier (NOT __syncthreads), so the
//     prefetch loads stay in flight across it (no vmcnt(0) drain).
//   - fp32->bf16 pack uses (__bf16) casts -> v_cvt_pk_bf16_f32 instead of the
//     ~9-op hand-rolled integer RNE sequence.

#define CCH   128
#define HH    96
#define WW    320
#define HWs   (HH * WW)      // 30720
#define CHWs  (CCH * HWs)
#define ND    81

#define TH 4      // output h rows per block
#define WT 32     // output w cols per block (2 M-tiles of 16)
#define SW 40     // staged x2 cols: W0-4 .. W0+35
#define SR 12     // staged x2 rows: h0-4 .. h0+7
#define KC 32     // channels per chunk (one MFMA K-step)
#define KP 40     // padded k-stride in shorts: 80B rows -> 16B aligned, 2-way banks (free)
#define OP 132    // obuf d-slice stride in floats (128 + 4: de-conflicts band scatter)
#define BUFSH 19200  // shorts per LDS x2 buffer (38400 B); two buffers

typedef __attribute__((ext_vector_type(8))) short        short8;
typedef __attribute__((ext_vector_type(4))) float        floatx4;
typedef __attribute__((ext_vector_type(4))) unsigned int uint4v;

// fp32 -> bf16 RNE via native cast; compiler pairs these into v_cvt_pk_bf16_f32.
__device__ __forceinline__ unsigned int pk2(float lo, float hi) {
  unsigned short a = __builtin_bit_cast(unsigned short, (__bf16)lo);
  unsigned short b = __builtin_bit_cast(unsigned short, (__bf16)hi);
  return (unsigned int)a | ((unsigned int)b << 16);
}

// Barrier that does NOT drain vmcnt: waits only for our LDS writes, then
// syncs. Prefetched global loads stay in flight across it (m201 pattern).
__device__ __forceinline__ void pipe_barrier() {
  asm volatile("s_waitcnt lgkmcnt(0)" ::: "memory");
  __builtin_amdgcn_s_barrier();
  asm volatile("" ::: "memory");
}

__global__ __launch_bounds__(512, 3) void cost_volume_kernel(
    const float* __restrict__ x1g, const float* __restrict__ x2g,
    float* __restrict__ out)
{
  extern __shared__ char smem[];
  short* x2s  = (short*)smem;       // 2 x BUFSH shorts = 76800 B
  float* obuf = (float*)smem;       // aliases buffer 0 after the k-loop

  const int b  = blockIdx.x & 7;    // batch spread across XCDs for L2 locality
  const int g  = blockIdx.x >> 3;
  const int hs = g % 24;
  const int ws = g / 24;
  const int h0 = hs * TH;
  const int W0 = ws * WT;

  const int t    = threadIdx.x;
  const int wave = t >> 6;
  const int lane = t & 63;
  const int hl   = wave >> 1;   // 0..3: h row owned by this wave
  const int mt   = wave & 1;    // 0..1: M-tile owned by this wave
  const int q    = lane >> 4;   // quad
  const int ln   = lane & 15;

  const float* x1b = x1g + (size_t)b * CHWs;
  const float* x2b = x2g + (size_t)b * CHWs;

  // --- staging decode: x2 has SR*SW*(KC/8) = 1920 octet-units, 512 threads ---
  int x2_go[4], x2_lo[4];
#pragma unroll
  for (int s = 0; s < 4; ++s) {
    int u = t + s * 512;
    if (u < SR * SW * 4) {
      int j  = u % SW;
      int ro = u / SW;
      int o  = ro & 3;            // which 8-channel octet
      int r  = ro >> 2;           // staged row
      int gr = h0 - 4 + r;
      int gc = W0 - 4 + j;
      x2_lo[s] = (r * SW + j) * KP + o * 8;
      x2_go[s] = (gr >= 0 && gr < HH && gc >= 0 && gc < WW)
                   ? (o * 8 * HWs + gr * WW + gc) : -1;
    } else { x2_lo[s] = -1; x2_go[s] = -1; }
  }
  const int x1off = (h0 + hl) * WW + W0 + mt * 16 + ln;

  float xr[4][8];   // x2 prefetch registers: one chunk in flight (32 VGPR)
  float xa[8];      // x1 prefetch registers (8 VGPR)
  short8 af;        // packed A-frag for the current chunk

  // issue chunk kc's global loads into registers (no waits here)
  auto issue = [&](int kc) {
    const int cbase = kc * KC * HWs;
    const float* p1 = x1b + cbase + q * 8 * HWs + x1off;
#pragma unroll
    for (int i = 0; i < 8; ++i) xa[i] = p1[i * HWs];
#pragma unroll
    for (int s = 0; s < 4; ++s)
      if (x2_go[s] >= 0) {
        const float* p = x2b + cbase + x2_go[s];
#pragma unroll
        for (int i = 0; i < 8; ++i) xr[s][i] = p[i * HWs];
      }
  };

  // convert chunk kc's registers to bf16, write x2 tile to LDS buf[kc&1],
  // and build this chunk's A-frag
  auto packw = [&](int kc) {
    short* dst = x2s + (kc & 1) * BUFSH;
#pragma unroll
    for (int s = 0; s < 4; ++s)
      if (x2_lo[s] >= 0) {
        uint4v v = (uint4v){0u, 0u, 0u, 0u};
        if (x2_go[s] >= 0)
          v = (uint4v){pk2(xr[s][0], xr[s][1]), pk2(xr[s][2], xr[s][3]),
                       pk2(xr[s][4], xr[s][5]), pk2(xr[s][6], xr[s][7])};
        *(uint4v*)&dst[x2_lo[s]] = v;
      }
    uint4v av = (uint4v){pk2(xa[0], xa[1]), pk2(xa[2], xa[3]),
                         pk2(xa[4], xa[5]), pk2(xa[6], xa[7])};
    af = *(short8*)&av;
  };

  floatx4 acc[9][2] = {};   // 72 AGPRs, persist across k-chunks

  // prologue: chunk 0 staged the slow way (nothing to overlap with yet)
  issue(0);
  packw(0);

  // steady state, per chunk: [issue k+1] [barrier] [MFMA k || pack k+1]
#pragma unroll
  for (int kc = 0; kc < CCH / KC; ++kc) {
    if (kc < CCH / KC - 1) issue(kc + 1);
    pipe_barrier();                       // buf[kc&1] now visible to all waves
    const short* src = x2s + (kc & 1) * BUFSH;
    const short8 a_cur = af;
#pragma unroll
    for (int dyi = 0; dyi < 9; ++dyi) {
      const int r = hl + dyi;             // staged row = h + dy (shifted +4)
#pragma unroll
      for (int jn = 0; jn < 2; ++jn) {
        int jc = (mt + jn) * 16 + ln;
        if (jc > SW - 1) jc = SW - 1;     // clamped lanes are never extracted
        const short8 bf = *(const short8*)&src[(r * SW + jc) * KP + q * 8];
        acc[dyi][jn] = __builtin_amdgcn_mfma_f32_16x16x32_bf16(a_cur, bf, acc[dyi][jn], 0, 0, 0);
      }
    }
    if (kc < CCH / KC - 1) packw(kc + 1); // waits vmcnt as needed; writes buf[(kc+1)&1]
  }

  // ---- epilogue: extract diagonal band dx+4 = jn*16 + n - m, two d-phases ----
  // obuf aliases buffer 0; last MFMA read buffer 1, so no barrier needed before
  // the first scatter (disjoint LDS ranges).
  const size_t obase = (size_t)b * (ND * (size_t)HWs);
#pragma unroll
  for (int ph = 0; ph < 2; ++ph) {
    const int d0 = ph ? 5 : 0, d1 = ph ? 9 : 5;     // dyi range
#pragma unroll
    for (int dyi = 0; dyi < 9; ++dyi) {
      if (dyi < d0 || dyi >= d1) continue;
#pragma unroll
      for (int jn = 0; jn < 2; ++jn)
#pragma unroll
        for (int reg = 0; reg < 4; ++reg) {
          const int m   = q * 4 + reg;
          const int dxi = jn * 16 + ln - m;
          if (dxi >= 0 && dxi < 9) {
            float v = acc[dyi][jn][reg] * (1.0f / 128.0f);
            v = (v < 0.0f) ? 0.1f * v : v;
            obuf[((dyi - d0) * 9 + dxi) * OP + hl * WT + mt * 16 + m] = v;
          }
        }
    }
    __syncthreads();
    const int nd   = (d1 - d0) * 9;           // 45 then 36 d-slices
    const int dbas = d0 * 9;
    for (int idx = t; idx < nd * TH * WT; idx += 512) {
      const int dl  = idx >> 7;               // /(TH*WT)=128
      const int rem = idx & 127;
      const int hh  = rem >> 5;
      const int wl  = rem & 31;
      out[obase + (size_t)(dbas + dl) * HWs + (h0 + hh) * WW + W0 + wl]
          = obuf[dl * OP + rem];
    }
    __syncthreads();
  }
}

extern "C" void kernel_launch(void* const* d_in, const int* in_sizes, int n_in,
                              void* d_out, int out_size, void* d_ws, size_t ws_size,
                              hipStream_t stream) {
  const float* x1 = (const float*)d_in[0];
  const float* x2 = (const float*)d_in[1];
  float* out = (float*)d_out;
  // grid: 8 batches x 24 h-strips x 10 w-tiles = 1920 blocks
  cost_volume_kernel<<<dim3(1920), dim3(512), 2 * 38400, stream>>>(x1, x2, out);
}

// Round 2
// 317.682 us; speedup vs baseline: 1.2115x; 1.2115x over previous
//
#include <hip/hip_runtime.h>
#include <stdint.h>

// CostVolume: out[b, d=(dy+4)*9+(dx+4), h, w] =
//   leaky_relu( mean_c( x1[b,c,h,w] * x2[b,c,h+dy,w+dx] ), 0.1 ), zero-padded x2.
//
// R2 design: two-kernel scheme.
//  1) x2_prepass: fp32 [b][c][h][w] -> bf16 ws layout [b][kc4][h][w][32ch],
//     64 B/pixel, with octet q stored at 16B-slot (q + ((gc+4)>>1)) & 3.
//     Swizzle is block-invariant (W0 % 32 == 0) and makes the main kernel's
//     B-frag ds_read_b128 a 2-way (free) bank pattern while the LDS image of
//     the tile stays LINEAR -> global_load_lds DMA staging works.
//  2) cost_volume_main: per chunk stages the 12x40 x2 halo tile with FOUR
//     global_load_lds dwordx4 per wave (no staging regs, no staging VALU),
//     double-buffered, one vmcnt(0)+s_barrier per chunk; DMA(k+1) issued
//     right after the barrier so it hides under MFMA(k). x1 stays fp32
//     (8 strided loads + 4 cvt_pk per chunk).
// Fallback to the harness-proven R0 kernel when ws_size < 63 MB.

#define CCH   128
#define HH    96
#define WW    320
#define HWs   (HH * WW)      // 30720
#define CHWs  (CCH * HWs)
#define ND    81

#define TH 4      // output h rows per block
#define WT 32     // output w cols per block (2 M-tiles of 16)
#define SW 40     // staged x2 cols: W0-4 .. W0+35
#define SR 12     // staged x2 rows: h0-4 .. h0+7
#define KC 32     // channels per chunk (one MFMA K-step)
#define OP 132    // obuf d-slice stride in floats (128 + 4: de-conflicts band scatter)

#define BUFB       30720            // bytes per LDS x2 buffer (12*40*64)
#define X2WS_BYTES (8u*4u*96u*320u*64u)   // 62914560
#define ZPAGE_OFF  X2WS_BYTES
#define WS_NEED    (X2WS_BYTES + 4096u)
#define CHUNK_STEP (96*320*64)      // 1966080 B per kc in ws

typedef __attribute__((ext_vector_type(8))) short        short8;
typedef __attribute__((ext_vector_type(4))) float        floatx4;
typedef __attribute__((ext_vector_type(4))) unsigned int uint4v;

// fp32 -> bf16 RNE via native cast; compiler pairs these into v_cvt_pk_bf16_f32.
__device__ __forceinline__ unsigned int pk2(float lo, float hi) {
  unsigned short a = __builtin_bit_cast(unsigned short, (__bf16)lo);
  unsigned short b = __builtin_bit_cast(unsigned short, (__bf16)hi);
  return (unsigned int)a | ((unsigned int)b << 16);
}

#define GLOAD_LDS16(gp, lp) __builtin_amdgcn_global_load_lds(              \
    (const __attribute__((address_space(1))) void*)(gp),                   \
    (__attribute__((address_space(3))) void*)(lp), 16, 0, 0)

// ---------------------------------------------------------------------------
// Pre-pass: x2 fp32 -> bf16 slot-swizzled ws.  grid 8*4*96 blocks x 320 thr.
// Thread = one column gc of one (b, kc, h) row: 32 strided dword reads
// (lane-coalesced along gc), 16 cvt_pk, 4 global_store_dwordx4.
// ---------------------------------------------------------------------------
__global__ __launch_bounds__(320) void x2_prepass(
    const float* __restrict__ x2g, char* __restrict__ ws)
{
  const int idx = blockIdx.x;
  const int h  = idx % 96;
  const int kc = (idx / 96) & 3;
  const int b  = idx / 384;
  const int gc = threadIdx.x;         // 0..319

  const float* src = x2g + (size_t)b * CHWs + (size_t)(kc * 32) * HWs
                   + h * WW + gc;
  float v[32];
#pragma unroll
  for (int c = 0; c < 32; ++c) v[c] = src[c * HWs];

  char* dst = ws + ((size_t)((b * 4 + kc) * 96 + h) * 320 + gc) * 64;
  const int hgc = ((gc + 4) >> 1) & 3;
#pragma unroll
  for (int q = 0; q < 4; ++q) {
    uint4v w = (uint4v){pk2(v[8*q+0], v[8*q+1]), pk2(v[8*q+2], v[8*q+3]),
                        pk2(v[8*q+4], v[8*q+5]), pk2(v[8*q+6], v[8*q+7])};
    const int s = (q + hgc) & 3;      // runtime ADDRESS, static reg indexing
    *(uint4v*)(dst + s * 16) = w;
  }

  // zero page for OOB DMA lanes (1024 B is enough; write 4096 for safety)
  if (idx == 0 && threadIdx.x < 256)
    *(uint4v*)(ws + ZPAGE_OFF + threadIdx.x * 16) = (uint4v){0u, 0u, 0u, 0u};
}

// ---------------------------------------------------------------------------
// Main kernel: DMA-staged, double-buffered.
// ---------------------------------------------------------------------------
__global__ __launch_bounds__(512, 4) void cost_volume_main(
    const float* __restrict__ x1g, const char* __restrict__ ws2,
    float* __restrict__ out)
{
  extern __shared__ char smem[];
  short* x2s  = (short*)smem;         // 2 x 30720 B double buffer
  float* obuf = (float*)smem;         // aliases buffer 0 after k-loop

  const int b  = blockIdx.x & 7;      // batch spread across XCDs
  const int g  = blockIdx.x >> 3;
  const int hs = g % 24;
  const int wsx = g / 24;
  const int h0 = hs * TH;
  const int W0 = wsx * WT;

  const int t    = threadIdx.x;
  const int wave = t >> 6;
  const int lane = t & 63;
  const int hl   = wave >> 1;
  const int mt   = wave & 1;
  const int q    = lane >> 4;
  const int ln   = lane & 15;

  // --- DMA decode: 1920 16B-units = 30 wave-instructions; wave w issues
  //     insts w*4+si (wave 7 issues only 2). unit = inst*64 + lane. ---
  unsigned int off[4];
  unsigned int vm = 0;                // bit si: unit maps to a real pixel
#pragma unroll
  for (int si = 0; si < 4; ++si) {
    const int iid = wave * 4 + si;
    if (iid < 30) {
      const int unit = iid * 64 + lane;
      const int r  = unit / 160;
      const int rem = unit - r * 160;
      const int j  = rem >> 2;
      const int s  = rem & 3;
      const int gr = h0 - 4 + r;
      const int gc = W0 - 4 + j;
      const bool inb = (gr >= 0 && gr < HH && gc >= 0 && gc < WW);
      off[si] = inb ? (unsigned)(((b * 4) * HH + gr) * WW + gc) * 64u + s * 16u
                    : (unsigned)(ZPAGE_OFF + s * 16u);
      if (inb) vm |= (1u << si);
    } else off[si] = ZPAGE_OFF;
  }

  const float* x1b  = x1g + (size_t)b * CHWs;
  const int    x1off = (h0 + hl) * WW + W0 + mt * 16 + ln;

  auto issue_dma = [&](int kc1) {
    char* lb = smem + (kc1 & 1) * BUFB + wave * 4096;
#pragma unroll
    for (int si = 0; si < 4; ++si) {
      if (wave * 4 + si < 30) {                  // wave-uniform predicate
        GLOAD_LDS16(ws2 + off[si], lb + si * 1024);
        off[si] += (vm >> si & 1u) ? (unsigned)CHUNK_STEP : 0u;
      }
    }
  };

  float xa[8];
  auto issue_x1 = [&](int kc1) {
    const float* p1 = x1b + kc1 * KC * HWs + q * 8 * HWs + x1off;
#pragma unroll
    for (int i = 0; i < 8; ++i) xa[i] = p1[i * HWs];
  };

  floatx4 acc[9][2] = {};   // 72 AGPRs

  issue_dma(0);
  issue_x1(0);

#pragma unroll
  for (int kc = 0; kc < CCH / KC; ++kc) {
    // pack A-frag (compiler waits its own x1 loads); then ensure OUR DMA(kc)
    // retired before the barrier.
    uint4v av = (uint4v){pk2(xa[0], xa[1]), pk2(xa[2], xa[3]),
                         pk2(xa[4], xa[5]), pk2(xa[6], xa[7])};
    const short8 af = *(short8*)&av;
    asm volatile("s_waitcnt vmcnt(0)" ::: "memory");
    __builtin_amdgcn_s_barrier();
    asm volatile("" ::: "memory");    // keep DMA(kc+1)/reads below the barrier

    if (kc < CCH / KC - 1) { issue_dma(kc + 1); issue_x1(kc + 1); }

    const short* src = x2s + (kc & 1) * (BUFB / 2);
    __builtin_amdgcn_s_setprio(1);
#pragma unroll
    for (int dyi = 0; dyi < 9; ++dyi) {
      const int r = hl + dyi;           // staged row = h + dy (shifted +4)
#pragma unroll
      for (int jn = 0; jn < 2; ++jn) {
        int j = (mt + jn) * 16 + ln;
        if (j > SW - 1) j = SW - 1;     // clamped lanes are never extracted
        const int slot = (q + (j >> 1)) & 3;
        const short8 bf = *(const short8*)&src[((r * SW + j) * 4 + slot) * 8];
        acc[dyi][jn] = __builtin_amdgcn_mfma_f32_16x16x32_bf16(af, bf, acc[dyi][jn], 0, 0, 0);
      }
    }
    __builtin_amdgcn_s_setprio(0);
  }

  // ---- epilogue: extract diagonal band dx+4 = jn*16 + n - m, two d-phases.
  // obuf = [0,23760) subset of buffer 0; last MFMA read buffer 1 -> disjoint.
  const size_t obase = (size_t)b * (ND * (size_t)HWs);
#pragma unroll
  for (int ph = 0; ph < 2; ++ph) {
    const int d0 = ph ? 5 : 0, d1 = ph ? 9 : 5;
#pragma unroll
    for (int dyi = 0; dyi < 9; ++dyi) {
      if (dyi < d0 || dyi >= d1) continue;
#pragma unroll
      for (int jn = 0; jn < 2; ++jn)
#pragma unroll
        for (int reg = 0; reg < 4; ++reg) {
          const int m   = q * 4 + reg;
          const int dxi = jn * 16 + ln - m;
          if (dxi >= 0 && dxi < 9) {
            float v = acc[dyi][jn][reg] * (1.0f / 128.0f);
            v = (v < 0.0f) ? 0.1f * v : v;
            obuf[((dyi - d0) * 9 + dxi) * OP + hl * WT + mt * 16 + m] = v;
          }
        }
    }
    __syncthreads();
    const int nd   = (d1 - d0) * 9;
    const int dbas = d0 * 9;
    for (int idx = t; idx < nd * TH * WT; idx += 512) {
      const int dl  = idx >> 7;
      const int rem = idx & 127;
      const int hh  = rem >> 5;
      const int wl  = rem & 31;
      out[obase + (size_t)(dbas + dl) * HWs + (h0 + hh) * WW + W0 + wl]
          = obuf[dl * OP + rem];
    }
    __syncthreads();
  }
}

// ---------------------------------------------------------------------------
// Fallback (harness-proven R0 kernel) when ws_size is too small.
// ---------------------------------------------------------------------------
#define KP 40
__global__ __launch_bounds__(512, 4) void cost_volume_fallback(
    const float* __restrict__ x1g, const float* __restrict__ x2g,
    float* __restrict__ out)
{
  extern __shared__ char smem[];
  short* x2s  = (short*)smem;
  float* obuf = (float*)smem;

  const int b  = blockIdx.x & 7;
  const int g  = blockIdx.x >> 3;
  const int hs = g % 24;
  const int wsx = g / 24;
  const int h0 = hs * TH;
  const int W0 = wsx * WT;

  const int t    = threadIdx.x;
  const int wave = t >> 6;
  const int lane = t & 63;
  const int hl   = wave >> 1;
  const int mt   = wave & 1;
  const int q    = lane >> 4;
  const int ln   = lane & 15;

  const float* x1b = x1g + (size_t)b * CHWs;
  const float* x2b = x2g + (size_t)b * CHWs;

  int x2_go[4], x2_lo[4];
#pragma unroll
  for (int s = 0; s < 4; ++s) {
    int u = t + s * 512;
    if (u < SR * SW * 4) {
      int j  = u % SW;
      int ro = u / SW;
      int o  = ro & 3;
      int r  = ro >> 2;
      int gr = h0 - 4 + r;
      int gc = W0 - 4 + j;
      x2_lo[s] = (r * SW + j) * KP + o * 8;
      x2_go[s] = (gr >= 0 && gr < HH && gc >= 0 && gc < WW)
                   ? (o * 8 * HWs + gr * WW + gc) : -1;
    } else { x2_lo[s] = -1; x2_go[s] = -1; }
  }
  const int x1off = (h0 + hl) * WW + W0 + mt * 16 + ln;

  floatx4 acc[9][2] = {};

  for (int kc = 0; kc < CCH / KC; ++kc) {
    const int cbase = kc * KC * HWs;
    const float* p1 = x1b + cbase + (size_t)q * 8 * HWs + x1off;
    float a0 = p1[0 * HWs], a1 = p1[1 * HWs], a2 = p1[2 * HWs], a3 = p1[3 * HWs];
    float a4 = p1[4 * HWs], a5 = p1[5 * HWs], a6 = p1[6 * HWs], a7 = p1[7 * HWs];

#pragma unroll
    for (int s = 0; s < 4; ++s) {
      if (x2_lo[s] >= 0) {
        unsigned int p01 = 0, p23 = 0, p45 = 0, p67 = 0;
        if (x2_go[s] >= 0) {
          const float* p = x2b + cbase + x2_go[s];
          float f0 = p[0 * HWs], f1 = p[1 * HWs], f2 = p[2 * HWs], f3 = p[3 * HWs];
          float f4 = p[4 * HWs], f5 = p[5 * HWs], f6 = p[6 * HWs], f7 = p[7 * HWs];
          p01 = pk2(f0, f1); p23 = pk2(f2, f3);
          p45 = pk2(f4, f5); p67 = pk2(f6, f7);
        }
        *(uint4v*)&x2s[x2_lo[s]] = (uint4v){p01, p23, p45, p67};
      }
    }

    short8 af;
    {
      uint4v av = (uint4v){pk2(a0, a1), pk2(a2, a3), pk2(a4, a5), pk2(a6, a7)};
      af = *(short8*)&av;
    }
    __syncthreads();

#pragma unroll
    for (int dyi = 0; dyi < 9; ++dyi) {
      const int r = hl + dyi;
#pragma unroll
      for (int jn = 0; jn < 2; ++jn) {
        int jc = (mt + jn) * 16 + ln;
        if (jc > SW - 1) jc = SW - 1;
        const short8 bf = *(const short8*)&x2s[(r * SW + jc) * KP + q * 8];
        acc[dyi][jn] = __builtin_amdgcn_mfma_f32_16x16x32_bf16(af, bf, acc[dyi][jn], 0, 0, 0);
      }
    }
    __syncthreads();
  }

  const size_t obase = (size_t)b * (ND * (size_t)HWs);
#pragma unroll
  for (int ph = 0; ph < 2; ++ph) {
    const int d0 = ph ? 5 : 0, d1 = ph ? 9 : 5;
#pragma unroll
    for (int dyi = 0; dyi < 9; ++dyi) {
      if (dyi < d0 || dyi >= d1) continue;
#pragma unroll
      for (int jn = 0; jn < 2; ++jn)
#pragma unroll
        for (int reg = 0; reg < 4; ++reg) {
          const int m   = q * 4 + reg;
          const int dxi = jn * 16 + ln - m;
          if (dxi >= 0 && dxi < 9) {
            float v = acc[dyi][jn][reg] * (1.0f / 128.0f);
            v = (v < 0.0f) ? 0.1f * v : v;
            obuf[((dyi - d0) * 9 + dxi) * OP + hl * WT + mt * 16 + m] = v;
          }
        }
    }
    __syncthreads();
    const int nd   = (d1 - d0) * 9;
    const int dbas = d0 * 9;
    for (int idx = t; idx < nd * TH * WT; idx += 512) {
      const int dl  = idx >> 7;
      const int rem = idx & 127;
      const int hh  = rem >> 5;
      const int wl  = rem & 31;
      out[obase + (size_t)(dbas + dl) * HWs + (h0 + hh) * WW + W0 + wl]
          = obuf[dl * OP + rem];
    }
    __syncthreads();
  }
}

extern "C" void kernel_launch(void* const* d_in, const int* in_sizes, int n_in,
                              void* d_out, int out_size, void* d_ws, size_t ws_size,
                              hipStream_t stream) {
  const float* x1 = (const float*)d_in[0];
  const float* x2 = (const float*)d_in[1];
  float* out = (float*)d_out;
  if (ws_size >= (size_t)WS_NEED && d_ws != nullptr) {
    x2_prepass<<<dim3(8 * 4 * 96), dim3(320), 0, stream>>>(x2, (char*)d_ws);
    cost_volume_main<<<dim3(1920), dim3(512), 2 * BUFB, stream>>>(
        x1, (const char*)d_ws, out);
  } else {
    cost_volume_fallback<<<dim3(1920), dim3(512), 38400, stream>>>(x1, x2, out);
  }
}

// Round 3
// 313.674 us; speedup vs baseline: 1.2270x; 1.0128x over previous
//
#include <hip/hip_runtime.h>
#include <stdint.h>

// CostVolume: out[b, d=(dy+4)*9+(dx+4), h, w] =
//   leaky_relu( mean_c( x1[b,c,h,w] * x2[b,c,h+dy,w+dx] ), 0.1 ), zero-padded x2.
//
// R3: two-kernel scheme.
//  1) x2_prepass (LDS-transpose version): fp32 [b][c][h][w] -> bf16 ws layout
//     [b][kc4][pixel][32ch] (64 B/pixel), octet q at 16B-slot (q+((gc+4)>>1))&3.
//     All global reads are 1KB-contiguous float4 runs (one channel row per wave
//     instr), all writes contiguous dwordx4 -- the m13-proven BW pattern.
//     (R2's strided-dword prepass ran at 2.1 TB/s; this targets >5 TB/s.)
//  2) cost_volume_main: per chunk stages the 12x40 x2 halo tile with FOUR
//     global_load_lds dwordx4 per wave (no staging regs/VALU), double-buffered,
//     one vmcnt(0)+s_barrier per chunk; DMA(k+1) issued right after the barrier
//     hides under MFMA(k). Epilogue band-transpose now scatters float4.
// Fallback to the harness-proven R0 kernel when ws_size < 63 MB.

#define CCH   128
#define HH    96
#define WW    320
#define HWs   (HH * WW)      // 30720
#define CHWs  (CCH * HWs)
#define ND    81

#define TH 4      // output h rows per block
#define WT 32     // output w cols per block (2 M-tiles of 16)
#define SW 40     // staged x2 cols: W0-4 .. W0+35
#define SR 12     // staged x2 rows: h0-4 .. h0+7
#define KC 32     // channels per chunk (one MFMA K-step)
#define OP 132    // obuf d-slice stride in floats (128 + 4: de-conflicts band scatter)

#define BUFB       30720            // bytes per LDS x2 buffer (12*40*64)
#define X2WS_BYTES (8u*4u*96u*320u*64u)   // 62914560
#define ZPAGE_OFF  X2WS_BYTES
#define WS_NEED    (X2WS_BYTES + 4096u)
#define CHUNK_STEP (96*320*64)      // 1966080 B per kc in ws

typedef __attribute__((ext_vector_type(8))) short        short8;
typedef __attribute__((ext_vector_type(4))) float        floatx4;
typedef __attribute__((ext_vector_type(4))) unsigned int uint4v;

// fp32 -> bf16 RNE via native cast; compiler pairs these into v_cvt_pk_bf16_f32.
__device__ __forceinline__ unsigned int pk2(float lo, float hi) {
  unsigned short a = __builtin_bit_cast(unsigned short, (__bf16)lo);
  unsigned short b = __builtin_bit_cast(unsigned short, (__bf16)hi);
  return (unsigned int)a | ((unsigned int)b << 16);
}

#define GLOAD_LDS16(gp, lp) __builtin_amdgcn_global_load_lds(              \
    (const __attribute__((address_space(1))) void*)(gp),                   \
    (__attribute__((address_space(3))) void*)(lp), 16, 0, 0)

// ---------------------------------------------------------------------------
// Pre-pass v2: LDS-transpose. Grid = 32 planes x 120 tiles = 3840 blocks x 256.
// Per block: read 32ch x 256px fp32 (contiguous float4 per wave instr),
// transpose in LDS, write 256 px x 64 B bf16 units (contiguous dwordx4).
// ---------------------------------------------------------------------------
#define TPX  256
#define LSTR 260   // LDS row stride in dwords: keeps float4 16B-aligned

__global__ __launch_bounds__(256) void x2_prepass(
    const float* __restrict__ x2g, char* __restrict__ ws)
{
  __shared__ float lds[32 * LSTR];   // 33280 B -> 4 blocks/CU
  const int blk  = blockIdx.x;
  const int pi   = blk / 120;        // plane: b*4 + kc
  const int tile = blk % 120;
  const int p0   = tile * TPX;
  const int b    = pi >> 2;
  const int kc   = pi & 3;
  const int t    = threadIdx.x;

  const float* src = x2g + (size_t)b * CHWs + (size_t)(kc * 32) * HWs + p0;
#pragma unroll
  for (int j = 0; j < 8; ++j) {
    const int f = t + j * 256;       // float4 index in [0, 2048)
    const int c = f >> 6;            // 64 float4 per channel row
    const int i = f & 63;
    const floatx4 v = *(const floatx4*)(src + (size_t)c * HWs + i * 4);
    *(floatx4*)&lds[c * LSTR + i * 4] = v;
  }
  __syncthreads();

  char* dstp = ws + ((size_t)pi * HWs + p0) * 64;
#pragma unroll
  for (int j = 0; j < 4; ++j) {
    const int u  = t + j * 256;      // unit in [0, 1024): q fastest, then px
    const int q  = u & 3;
    const int px = u >> 2;
    const float* rp = &lds[(q * 8) * LSTR + px];
    uint4v w = (uint4v){pk2(rp[0*LSTR], rp[1*LSTR]), pk2(rp[2*LSTR], rp[3*LSTR]),
                        pk2(rp[4*LSTR], rp[5*LSTR]), pk2(rp[6*LSTR], rp[7*LSTR])};
    const int gc = (p0 + px) % 320;
    const int s  = (q + ((gc + 4) >> 1)) & 3;   // bank swizzle slot
    *(uint4v*)(dstp + px * 64 + s * 16) = w;
  }

  // zero page for OOB DMA lanes
  if (blk == 0)
    *(uint4v*)(ws + ZPAGE_OFF + t * 16) = (uint4v){0u, 0u, 0u, 0u};
}

// ---------------------------------------------------------------------------
// Main kernel: DMA-staged, double-buffered (structure proven in R2).
// ---------------------------------------------------------------------------
__global__ __launch_bounds__(512, 4) void cost_volume_main(
    const float* __restrict__ x1g, const char* __restrict__ ws2,
    float* __restrict__ out)
{
  extern __shared__ char smem[];
  short* x2s  = (short*)smem;         // 2 x 30720 B double buffer
  float* obuf = (float*)smem;         // aliases buffer 0 after k-loop

  const int b  = blockIdx.x & 7;      // batch spread across XCDs
  const int g  = blockIdx.x >> 3;
  const int hs = g % 24;
  const int wsx = g / 24;
  const int h0 = hs * TH;
  const int W0 = wsx * WT;

  const int t    = threadIdx.x;
  const int wave = t >> 6;
  const int lane = t & 63;
  const int hl   = wave >> 1;
  const int mt   = wave & 1;
  const int q    = lane >> 4;
  const int ln   = lane & 15;

  // --- DMA decode: 1920 16B-units = 30 wave-instructions; wave w issues
  //     insts w*4+si (wave 7 issues only 2). unit = inst*64 + lane. ---
  unsigned int off[4];
  unsigned int vm = 0;
#pragma unroll
  for (int si = 0; si < 4; ++si) {
    const int iid = wave * 4 + si;
    if (iid < 30) {
      const int unit = iid * 64 + lane;
      const int r  = unit / 160;
      const int rem = unit - r * 160;
      const int j  = rem >> 2;
      const int s  = rem & 3;
      const int gr = h0 - 4 + r;
      const int gc = W0 - 4 + j;
      const bool inb = (gr >= 0 && gr < HH && gc >= 0 && gc < WW);
      off[si] = inb ? (unsigned)(((b * 4) * HH + gr) * WW + gc) * 64u + s * 16u
                    : (unsigned)(ZPAGE_OFF + s * 16u);
      if (inb) vm |= (1u << si);
    } else off[si] = ZPAGE_OFF;
  }

  const float* x1b  = x1g + (size_t)b * CHWs;
  const int    x1off = (h0 + hl) * WW + W0 + mt * 16 + ln;

  auto issue_dma = [&](int kc1) {
    char* lb = smem + (kc1 & 1) * BUFB + wave * 4096;
#pragma unroll
    for (int si = 0; si < 4; ++si) {
      if (wave * 4 + si < 30) {                  // wave-uniform predicate
        GLOAD_LDS16(ws2 + off[si], lb + si * 1024);
        off[si] += (vm >> si & 1u) ? (unsigned)CHUNK_STEP : 0u;
      }
    }
  };

  float xa[8];
  auto issue_x1 = [&](int kc1) {
    const float* p1 = x1b + kc1 * KC * HWs + q * 8 * HWs + x1off;
#pragma unroll
    for (int i = 0; i < 8; ++i) xa[i] = p1[i * HWs];
  };

  floatx4 acc[9][2] = {};   // 72 AGPRs

  issue_dma(0);
  issue_x1(0);

#pragma unroll
  for (int kc = 0; kc < CCH / KC; ++kc) {
    uint4v av = (uint4v){pk2(xa[0], xa[1]), pk2(xa[2], xa[3]),
                         pk2(xa[4], xa[5]), pk2(xa[6], xa[7])};
    const short8 af = *(short8*)&av;
    asm volatile("s_waitcnt vmcnt(0)" ::: "memory");
    __builtin_amdgcn_s_barrier();
    asm volatile("" ::: "memory");    // keep DMA(kc+1)/reads below the barrier

    if (kc < CCH / KC - 1) { issue_dma(kc + 1); issue_x1(kc + 1); }

    const short* src = x2s + (kc & 1) * (BUFB / 2);
    __builtin_amdgcn_s_setprio(1);
#pragma unroll
    for (int dyi = 0; dyi < 9; ++dyi) {
      const int r = hl + dyi;           // staged row = h + dy (shifted +4)
#pragma unroll
      for (int jn = 0; jn < 2; ++jn) {
        int j = (mt + jn) * 16 + ln;
        if (j > SW - 1) j = SW - 1;     // clamped lanes are never extracted
        const int slot = (q + (j >> 1)) & 3;
        const short8 bf = *(const short8*)&src[((r * SW + j) * 4 + slot) * 8];
        acc[dyi][jn] = __builtin_amdgcn_mfma_f32_16x16x32_bf16(af, bf, acc[dyi][jn], 0, 0, 0);
      }
    }
    __builtin_amdgcn_s_setprio(0);
  }

  // ---- epilogue: extract diagonal band dx+4 = jn*16 + n - m, two d-phases.
  // obuf = [0,23760) subset of buffer 0; last MFMA read buffer 1 -> disjoint.
  const size_t obase = (size_t)b * (ND * (size_t)HWs);
#pragma unroll
  for (int ph = 0; ph < 2; ++ph) {
    const int d0 = ph ? 5 : 0, d1 = ph ? 9 : 5;
#pragma unroll
    for (int dyi = 0; dyi < 9; ++dyi) {
      if (dyi < d0 || dyi >= d1) continue;
#pragma unroll
      for (int jn = 0; jn < 2; ++jn)
#pragma unroll
        for (int reg = 0; reg < 4; ++reg) {
          const int m   = q * 4 + reg;
          const int dxi = jn * 16 + ln - m;
          if (dxi >= 0 && dxi < 9) {
            float v = acc[dyi][jn][reg] * (1.0f / 128.0f);
            v = (v < 0.0f) ? 0.1f * v : v;
            obuf[((dyi - d0) * 9 + dxi) * OP + hl * WT + mt * 16 + m] = v;
          }
        }
    }
    __syncthreads();
    // float4 scatter: unit u = (dl, hh, w4); obuf strides are 16B-aligned
    // (OP*4 = 528 B, hh*128 B, w4*16 B).
    const int nu   = (d1 - d0) * 9 * (TH * WT / 4);   // 1440 then 1152
    const int dbas = d0 * 9;
    for (int u = t; u < nu; u += 512) {
      const int dl = u >> 5;
      const int r4 = u & 31;
      const int hh = r4 >> 3;
      const int wl = (r4 & 7) * 4;
      const floatx4 v = *(const floatx4*)&obuf[dl * OP + hh * WT + wl];
      *(floatx4*)&out[obase + (size_t)(dbas + dl) * HWs + (h0 + hh) * WW + W0 + wl] = v;
    }
    __syncthreads();
  }
}

// ---------------------------------------------------------------------------
// Fallback (harness-proven R0 kernel) when ws_size is too small.
// ---------------------------------------------------------------------------
#define KP 40
__global__ __launch_bounds__(512, 4) void cost_volume_fallback(
    const float* __restrict__ x1g, const float* __restrict__ x2g,
    float* __restrict__ out)
{
  extern __shared__ char smem[];
  short* x2s  = (short*)smem;
  float* obuf = (float*)smem;

  const int b  = blockIdx.x & 7;
  const int g  = blockIdx.x >> 3;
  const int hs = g % 24;
  const int wsx = g / 24;
  const int h0 = hs * TH;
  const int W0 = wsx * WT;

  const int t    = threadIdx.x;
  const int wave = t >> 6;
  const int lane = t & 63;
  const int hl   = wave >> 1;
  const int mt   = wave & 1;
  const int q    = lane >> 4;
  const int ln   = lane & 15;

  const float* x1b = x1g + (size_t)b * CHWs;
  const float* x2b = x2g + (size_t)b * CHWs;

  int x2_go[4], x2_lo[4];
#pragma unroll
  for (int s = 0; s < 4; ++s) {
    int u = t + s * 512;
    if (u < SR * SW * 4) {
      int j  = u % SW;
      int ro = u / SW;
      int o  = ro & 3;
      int r  = ro >> 2;
      int gr = h0 - 4 + r;
      int gc = W0 - 4 + j;
      x2_lo[s] = (r * SW + j) * KP + o * 8;
      x2_go[s] = (gr >= 0 && gr < HH && gc >= 0 && gc < WW)
                   ? (o * 8 * HWs + gr * WW + gc) : -1;
    } else { x2_lo[s] = -1; x2_go[s] = -1; }
  }
  const int x1off = (h0 + hl) * WW + W0 + mt * 16 + ln;

  floatx4 acc[9][2] = {};

  for (int kc = 0; kc < CCH / KC; ++kc) {
    const int cbase = kc * KC * HWs;
    const float* p1 = x1b + cbase + (size_t)q * 8 * HWs + x1off;
    float a0 = p1[0 * HWs], a1 = p1[1 * HWs], a2 = p1[2 * HWs], a3 = p1[3 * HWs];
    float a4 = p1[4 * HWs], a5 = p1[5 * HWs], a6 = p1[6 * HWs], a7 = p1[7 * HWs];

#pragma unroll
    for (int s = 0; s < 4; ++s) {
      if (x2_lo[s] >= 0) {
        unsigned int p01 = 0, p23 = 0, p45 = 0, p67 = 0;
        if (x2_go[s] >= 0) {
          const float* p = x2b + cbase + x2_go[s];
          float f0 = p[0 * HWs], f1 = p[1 * HWs], f2 = p[2 * HWs], f3 = p[3 * HWs];
          float f4 = p[4 * HWs], f5 = p[5 * HWs], f6 = p[6 * HWs], f7 = p[7 * HWs];
          p01 = pk2(f0, f1); p23 = pk2(f2, f3);
          p45 = pk2(f4, f5); p67 = pk2(f6, f7);
        }
        *(uint4v*)&x2s[x2_lo[s]] = (uint4v){p01, p23, p45, p67};
      }
    }

    short8 af;
    {
      uint4v av = (uint4v){pk2(a0, a1), pk2(a2, a3), pk2(a4, a5), pk2(a6, a7)};
      af = *(short8*)&av;
    }
    __syncthreads();

#pragma unroll
    for (int dyi = 0; dyi < 9; ++dyi) {
      const int r = hl + dyi;
#pragma unroll
      for (int jn = 0; jn < 2; ++jn) {
        int jc = (mt + jn) * 16 + ln;
        if (jc > SW - 1) jc = SW - 1;
        const short8 bf = *(const short8*)&x2s[(r * SW + jc) * KP + q * 8];
        acc[dyi][jn] = __builtin_amdgcn_mfma_f32_16x16x32_bf16(af, bf, acc[dyi][jn], 0, 0, 0);
      }
    }
    __syncthreads();
  }

  const size_t obase = (size_t)b * (ND * (size_t)HWs);
#pragma unroll
  for (int ph = 0; ph < 2; ++ph) {
    const int d0 = ph ? 5 : 0, d1 = ph ? 9 : 5;
#pragma unroll
    for (int dyi = 0; dyi < 9; ++dyi) {
      if (dyi < d0 || dyi >= d1) continue;
#pragma unroll
      for (int jn = 0; jn < 2; ++jn)
#pragma unroll
        for (int reg = 0; reg < 4; ++reg) {
          const int m   = q * 4 + reg;
          const int dxi = jn * 16 + ln - m;
          if (dxi >= 0 && dxi < 9) {
            float v = acc[dyi][jn][reg] * (1.0f / 128.0f);
            v = (v < 0.0f) ? 0.1f * v : v;
            obuf[((dyi - d0) * 9 + dxi) * OP + hl * WT + mt * 16 + m] = v;
          }
        }
    }
    __syncthreads();
    const int nd   = (d1 - d0) * 9;
    const int dbas = d0 * 9;
    for (int idx = t; idx < nd * TH * WT; idx += 512) {
      const int dl  = idx >> 7;
      const int rem = idx & 127;
      const int hh  = rem >> 5;
      const int wl  = rem & 31;
      out[obase + (size_t)(dbas + dl) * HWs + (h0 + hh) * WW + W0 + wl]
          = obuf[dl * OP + rem];
    }
    __syncthreads();
  }
}

extern "C" void kernel_launch(void* const* d_in, const int* in_sizes, int n_in,
                              void* d_out, int out_size, void* d_ws, size_t ws_size,
                              hipStream_t stream) {
  const float* x1 = (const float*)d_in[0];
  const float* x2 = (const float*)d_in[1];
  float* out = (float*)d_out;
  if (ws_size >= (size_t)WS_NEED && d_ws != nullptr) {
    x2_prepass<<<dim3(3840), dim3(256), 0, stream>>>(x2, (char*)d_ws);
    cost_volume_main<<<dim3(1920), dim3(512), 2 * BUFB, stream>>>(
        x1, (const char*)d_ws, out);
  } else {
    cost_volume_fallback<<<dim3(1920), dim3(512), 38400, stream>>>(x1, x2, out);
  }
}